// Round 4
// baseline (88.572 us; speedup 1.0000x reference)
//
#include <hip/hip_runtime.h>
#include <hip/hip_bf16.h>

// Problem constants (fixed by the reference).
#define BB 32
#define CC 32
#define PP 4096      // H*W
#define KS 9
#define KK 64        // output channels
#define CK 288       // C*KS

typedef __attribute__((ext_vector_type(8))) short short8;
typedef __attribute__((ext_vector_type(16))) float f32x16;

__device__ inline unsigned short f2bf(float f) {
    __hip_bfloat16 h = __float2bfloat16(f);
    return __builtin_bit_cast(unsigned short, h);
}

// ---- prep (merged): blocks [0,512) transpose x -> xt bf16 pixel-major
//      (1 pixel/thread, coalesced 256B/wave scalar loads, 64B row stores);
//      blocks [512,584) swizzle W -> wa bf16 in 32x32x16 A-fragment order.
// A-frag flat: i = (((kc*2 + kh)*2 + mt)*64 + l)*8 + j
//   -> A[m = ko = mt*32 + (l&31)][k = kh*16 + (l>>5)*8 + j  (channel c)]
//   value = w[ko][c*KS + kc]
__global__ __launch_bounds__(256)
void prep_kernel(const float* __restrict__ x, const float* __restrict__ w,
                 unsigned short* __restrict__ xt, unsigned short* __restrict__ wa) {
    const int t = threadIdx.x;
    const int blk = blockIdx.x;
    if (blk < 512) {
        const int b = blk >> 4;
        const int p = ((blk & 15) << 8) + t;
        const float* xb = x + (size_t)b * CC * PP + p;
        unsigned int buf[16];
#pragma unroll
        for (int c2 = 0; c2 < 16; ++c2) {
            float lo = xb[(size_t)(2 * c2) * PP];
            float hi = xb[(size_t)(2 * c2 + 1) * PP];
            buf[c2] = (unsigned int)f2bf(lo) | ((unsigned int)f2bf(hi) << 16);
        }
        uint4* dst = (uint4*)(xt + ((size_t)b * PP + p) * CC);
        const uint4* s = (const uint4*)buf;
#pragma unroll
        for (int j = 0; j < 4; ++j) dst[j] = s[j];
    } else {
        int i = (blk - 512) * 256 + t;
        if (i < KK * CK) {
            int j  = i & 7;
            int l  = (i >> 3) & 63;
            int mt = (i >> 9) & 1;
            int kh = (i >> 10) & 1;
            int kc = i >> 11;                       // 0..8
            int ko = (mt << 5) + (l & 31);
            int c  = (kh << 4) + ((l >> 5) << 3) + j;
            wa[i] = f2bf(w[ko * CK + c * KS + kc]);
        }
    }
}

// ---- main v5: 32x32x16 MFMA, bpermute-free. B-fragment lane map is n=l&31
// (pixel), k=(l>>5)*8+j -> the gathered dwordx4 (16B at row q[l&31], chunk
// kh*32B + (l>>5)*16B) IS the fragment, straight from global. A staged in
// LDS (36 KB), 4x ds_read_b128 per kc (only LDS traffic in the loop).
// Per kc: 2 gathers + 4 ds_read + 4 MFMA (was 2+8 bpermute+4+8).
// D layout (HW-verified): col=l&31=pixel, row=(r&3)+8*(r>>2)+4*(l>>5) ->
// every store instr covers two full 128-B lines. 3-deep gather pipeline.
// XCD swizzle unchanged: b = (blk&7)*4 + ((blk>>3)&3).
__global__ __launch_bounds__(256, 4)
void abc_mfma5_kernel(const unsigned short* __restrict__ xt,
                      const unsigned short* __restrict__ wa,
                      const int* __restrict__ idx,
                      float* __restrict__ out) {
    __shared__ unsigned short was[KK * CK];          // 36864 B
    const int t    = threadIdx.x;
    const int l    = t & 63;
    const int w    = t >> 6;
    const int blk  = blockIdx.x;
    const int b    = ((blk & 7) << 2) | ((blk >> 3) & 3);
    const int tile = blk >> 5;                               // 0..31
    const int p0   = (tile << 7) + (w << 5);                 // wave's 32 pixels
    const int gpix  = l & 31;                                // lane's pixel
    const int ghalf = l >> 5;                                // k-subgroup

    // stage wa -> LDS (2304 uint4, 9 per thread, coalesced)
    {
        const uint4* s = (const uint4*)wa;
        uint4* d = (uint4*)was;
#pragma unroll
        for (int j = 0; j < 9; ++j) d[t + 256 * j] = s[t + 256 * j];
    }

    const unsigned short* xtb = xt + (size_t)b * PP * CC;

    // neighbor indices for this lane's pixel (9 scalar loads, prologue-only)
    int q[KS];
    {
        const int* ip = idx + (size_t)(p0 + gpix) * KS;
#pragma unroll
        for (int kc = 0; kc < KS; ++kc) q[kc] = ip[kc];
    }

    f32x16 acc[2];   // [mt] : ko 0-31, 32-63
#pragma unroll
    for (int i = 0; i < 16; ++i) { acc[0][i] = 0.f; acc[1][i] = 0.f; }

    __syncthreads();

    // 3-deep register pipeline over kc; g[buf][kh] = 16B B-fragment
    short8 g[3][2];
#pragma unroll
    for (int kk = 0; kk < 2; ++kk)
#pragma unroll
        for (int kh = 0; kh < 2; ++kh)
            g[kk][kh] = *(const short8*)(xtb + (size_t)q[kk] * CC + (kh << 4) + (ghalf << 3));

#pragma unroll
    for (int kc = 0; kc < KS; ++kc) {
        if (kc + 2 < KS) {
            const int nb = (kc + 2) % 3;
#pragma unroll
            for (int kh = 0; kh < 2; ++kh)
                g[nb][kh] = *(const short8*)(xtb + (size_t)q[kc + 2] * CC + (kh << 4) + (ghalf << 3));
        }
        const int cb = kc % 3;
#pragma unroll
        for (int mt = 0; mt < 2; ++mt) {
#pragma unroll
            for (int kh = 0; kh < 2; ++kh) {
                const short8 a =
                    *(const short8*)(was + ((size_t)(((kc * 2 + kh) * 2 + mt) * 64 + l)) * 8);
                acc[mt] = __builtin_amdgcn_mfma_f32_32x32x16_bf16(a, g[cb][kh], acc[mt], 0, 0, 0);
            }
        }
    }

    // D: row = (r&3) + 8*(r>>2) + 4*ghalf (+32*mt), col(pixel) = gpix.
    // Each store: lanes 0-31 one full 128B line, lanes 32-63 another.
    float* ob = out + (size_t)b * KK * PP + p0 + gpix;
#pragma unroll
    for (int mt = 0; mt < 2; ++mt)
#pragma unroll
        for (int r = 0; r < 16; ++r) {
            const int row = (mt << 5) + (r & 3) + ((r >> 2) << 3) + (ghalf << 2);
            __builtin_nontemporal_store(acc[mt][r], ob + (size_t)row * PP);
        }
}

// ---- fallback (ws too small): round-2 VALU kernel ----
__global__ __launch_bounds__(256)
void abc_valu_kernel(const float* __restrict__ x, const float* __restrict__ w,
                     const int* __restrict__ idx, float* __restrict__ out) {
    __shared__ float xrow[PP];
    const int t = threadIdx.x;
    const int b = blockIdx.x >> 4;
    const int p = ((blockIdx.x & 15) << 8) + t;
    int q[KS];
#pragma unroll
    for (int k = 0; k < KS; ++k) q[k] = idx[p * KS + k];
    float acc[KK];
#pragma unroll
    for (int i = 0; i < KK; ++i) acc[i] = 0.0f;
    const float* xb = x + (size_t)b * CC * PP;
#pragma unroll 1
    for (int c = 0; c < CC; ++c) {
        const float4* src = (const float4*)(xb + (size_t)c * PP);
        float4* dst = (float4*)xrow;
#pragma unroll
        for (int j = 0; j < 4; ++j) dst[j * 256 + t] = src[j * 256 + t];
        __syncthreads();
        float xv[KS];
#pragma unroll
        for (int k = 0; k < KS; ++k) xv[k] = xrow[q[k]];
#pragma unroll
        for (int k = 0; k < KS; ++k) {
            const int col = c * KS + k;
#pragma unroll
            for (int ko = 0; ko < KK; ++ko)
                acc[ko] += xv[k] * w[ko * CK + col];
        }
        __syncthreads();
    }
    float* ob = out + (size_t)b * KK * PP + p;
#pragma unroll
    for (int ko = 0; ko < KK; ++ko)
        ob[(size_t)ko * PP] = acc[ko];
}

extern "C" void kernel_launch(void* const* d_in, const int* in_sizes, int n_in,
                              void* d_out, int out_size, void* d_ws, size_t ws_size,
                              hipStream_t stream) {
    const float* x  = (const float*)d_in[0];
    const float* w  = (const float*)d_in[1];
    const int* idx  = (const int*)d_in[2];
    float* out      = (float*)d_out;

    const size_t xt_bytes = (size_t)BB * PP * CC * 2;    // 8,388,608
    const size_t need     = xt_bytes + (size_t)KK * CK * 2;

    if (ws_size >= need) {
        unsigned short* xt = (unsigned short*)d_ws;
        unsigned short* wa = (unsigned short*)((char*)d_ws + xt_bytes);
        const int wb_blocks = (KK * CK + 255) / 256;     // 72
        prep_kernel<<<512 + wb_blocks, 256, 0, stream>>>(x, w, xt, wa);
        abc_mfma5_kernel<<<BB * (PP / 128), 256, 0, stream>>>(xt, wa, idx, out);
    } else {
        abc_valu_kernel<<<BB * (PP / 256), 256, 0, stream>>>(x, w, idx, out);
    }
}